// Round 7
// baseline (91.270 us; speedup 1.0000x reference)
//
#include <hip/hip_runtime.h>

// ---------------- problem constants ----------------
constexpr int B_ = 2, H_ = 512, W_ = 512;
constexpr int HWl = H_ * W_;          // 262144
constexpr int TOT = B_ * HWl;         // 524288
constexpr int KC = 200;               // TOP_K_INSTANCE
constexpr int CAPC = 65536;           // compacted candidate capacity
constexpr int NBLK = 256;             // k_nms blocks (128 row-tiles x 2 batches)
constexpr float INV2S2 = 0.0078125f;  // 1/128, exact power of 2

// output layout (flat float32, concatenated in return order)
constexpr int OUT_CENTER = 0;                 // [B,1,H,W]
constexpr int OUT_OFF = TOT;                  // [B,2,H,W]
constexpr int OUT_CW = 3 * TOT;               // [B,H,W] ones
constexpr int OUT_OW = 4 * TOT;               // [B,H,W] fg

__device__ __forceinline__ float hwthr(float v) { return v > 0.1f ? v : -1.0f; }
__device__ __forceinline__ float4 max4(float4 a, float4 b) {
  return make_float4(fmaxf(a.x, b.x), fmaxf(a.y, b.y), fmaxf(a.z, b.z), fmaxf(a.w, b.w));
}

// ---------------- kernels ----------------

// fused threshold + separable 7x7 NMS, LDS-tiled (4 output rows + 3-row halo).
// Peaks staged in LDS, written to a PER-BLOCK key segment with a plain bcount
// store -- no global atomics, no zero-init dependency.
__global__ __launch_bounds__(256) void k_nms(const float* __restrict__ ctr,
                                             unsigned long long* __restrict__ keys,
                                             int* __restrict__ bcount) {
  __shared__ float rmx[10 * 512];
  __shared__ unsigned long long lkeys[1024];
  __shared__ int lnum;
  int tid = threadIdx.x, blk = blockIdx.x;     // NBLK blocks
  int b = blk >> 7, y0 = (blk & 127) << 2;     // output rows y0..y0+3
  if (tid == 0) lnum = 0;
  const float4* c4p = (const float4*)(ctr + b * HWl);
  // horizontal 7-max of thresholded heatmap for rows y0-3 .. y0+6
  for (int u = tid; u < 1280; u += 256) {
    int r = u >> 7, c4 = u & 127, gy = y0 - 3 + r;
    float4 m = make_float4(-1e30f, -1e30f, -1e30f, -1e30f);
    if (gy >= 0 && gy < H_) {
      float4 v = c4p[gy * 128 + c4];
      float4 L = make_float4(-1e30f, -1e30f, -1e30f, -1e30f), R = L;
      if (c4 > 0) L = c4p[gy * 128 + c4 - 1];
      if (c4 < 127) R = c4p[gy * 128 + c4 + 1];
      float a1 = hwthr(L.y), a2 = hwthr(L.z), a3 = hwthr(L.w);
      float a4 = hwthr(v.x), a5 = hwthr(v.y), a6 = hwthr(v.z), a7 = hwthr(v.w);
      float a8 = hwthr(R.x), a9 = hwthr(R.y), a10 = hwthr(R.z);
      float core = fmaxf(fmaxf(a4, a5), fmaxf(a6, a7));
      m.x = fmaxf(fmaxf(a1, a2), fmaxf(a3, core));
      m.y = fmaxf(fmaxf(a2, a3), fmaxf(core, a8));
      m.z = fmaxf(fmaxf(a3, core), fmaxf(a8, a9));
      m.w = fmaxf(fmaxf(core, a8), fmaxf(a9, a10));
    }
    ((float4*)rmx)[u] = m;
  }
  __syncthreads();
  // vertical 7-max + peak emit
  for (int u = tid; u < 512; u += 256) {
    int orr = u >> 7, c4 = u & 127;
    int y = y0 + orr;
    float4 pool = ((float4*)rmx)[orr * 128 + c4];
#pragma unroll
    for (int r = 1; r <= 6; ++r)
      pool = max4(pool, ((float4*)rmx)[(orr + r) * 128 + c4]);
    float4 v = c4p[y * 128 + c4];
    float vv[4] = {v.x, v.y, v.z, v.w};
    float pv[4] = {pool.x, pool.y, pool.z, pool.w};
#pragma unroll
    for (int j = 0; j < 4; ++j) {
      float vj = vv[j];
      if (vj > 0.1f && vj == pv[j]) {  // exact equality, same as reference hmp==pooled
        unsigned int i = (unsigned int)(b * HWl + y * W_ + c4 * 4 + j);
        unsigned long long comp = ((unsigned long long)__float_as_uint(vj) << 32)
                                | (unsigned long long)(0xFFFFFFFFu - i);
        int slot = atomicAdd(&lnum, 1);  // LDS atomic, cheap
        if (slot < 1024) lkeys[slot] = comp;
      }
    }
  }
  __syncthreads();
  int n = lnum; if (n > 1024) n = 1024;
  if (tid == 0) bcount[blk] = n;
  for (int q = tid; q < n; q += 256) keys[blk * 1024 + q] = lkeys[q];
}

// exact top-K by (value desc, index asc): compact ALL NBLK segments, 4-level
// radix refine of the EXACT 32-bit rank-K value (12/8/8/4 bits), collect
// winners (<= K-1 + exact-value ties), rank-by-comparison -> rank order.
__global__ __launch_bounds__(1024) void k_topk(
    const unsigned long long* __restrict__ keys, const int* __restrict__ bcount,
    unsigned long long* __restrict__ keysc,
    float* __restrict__ cand_val, int* __restrict__ cand_bid,
    int* __restrict__ cand_cy, int* __restrict__ cand_cx) {
  __shared__ int hist[4096];
  __shared__ int sfxC[1024];
  __shared__ int hs[256];
  __shared__ int bc[NBLK], bpre[NBLK];
  __shared__ int s_bin, s_r, s_num, s_M;
  __shared__ unsigned long long wins[1024];
  int tid = threadIdx.x;

  // ---- prefix-sum ALL NBLK block counts, compact segments into keysc ----
  if (tid < NBLK) { int c = bcount[tid]; bc[tid] = c > 1024 ? 1024 : c; }
  __syncthreads();
  if (tid < NBLK) sfxC[tid] = bc[tid];
  __syncthreads();
  for (int off = 1; off < NBLK; off <<= 1) {
    int v = (tid < NBLK && tid >= off) ? sfxC[tid - off] : 0;
    __syncthreads();
    if (tid < NBLK) sfxC[tid] += v;
    __syncthreads();
  }
  if (tid < NBLK) bpre[tid] = sfxC[tid] - bc[tid];
  if (tid == 0) { int m = sfxC[NBLK - 1]; s_M = m > CAPC ? CAPC : m; }
  __syncthreads();
  int M = s_M;
  // main compaction: j < 128 covers essentially all segments (expected ~42/seg)
  for (int idx = tid; idx < NBLK * 128; idx += 1024) {
    int seg = idx >> 7, j = idx & 127;
    if (j < bc[seg]) {
      int dst = bpre[seg] + j;
      if (dst < CAPC) keysc[dst] = keys[seg * 1024 + j];
    }
  }
  // rare fallback for overfull segments
  for (int seg = 0; seg < NBLK; ++seg) {
    int c = bc[seg];
    if (c > 128) {
      for (int j = 128 + tid; j < c; j += 1024) {
        int dst = bpre[seg] + j;
        if (dst < CAPC) keysc[dst] = keys[seg * 1024 + j];
      }
    }
  }
  __threadfence();
  __syncthreads();

  int Kt = M < KC ? M : KC;
  unsigned long long thresh64 = 1ULL;  // M<=K: take everything (all keys nonzero)
  if (M > KC) {
    // ---- level 1: 4096 bins on composite bits [63:52] ----
    for (int q = tid; q < 4096; q += 1024) hist[q] = 0;
    __syncthreads();
    for (int idx = tid; idx < M; idx += 1024)
      atomicAdd(&hist[(int)(keysc[idx] >> 52)], 1);
    __syncthreads();
    int h0 = hist[4 * tid], h1 = hist[4 * tid + 1];
    int h2 = hist[4 * tid + 2], h3 = hist[4 * tid + 3];
    sfxC[tid] = h0 + h1 + h2 + h3;
    __syncthreads();
    for (int off = 1; off < 1024; off <<= 1) {
      int v = (tid + off < 1024) ? sfxC[tid + off] : 0;
      __syncthreads();
      sfxC[tid] += v;
      __syncthreads();
    }
    if (sfxC[tid] >= Kt && (tid == 1023 || sfxC[tid + 1] < Kt)) {
      int above = (tid == 1023) ? 0 : sfxC[tid + 1];
      int s3 = above + h3, s2 = s3 + h2, s1 = s2 + h1;
      int j, sAbove;
      if (s3 >= Kt)      { j = 3; sAbove = above; }
      else if (s2 >= Kt) { j = 2; sAbove = s3; }
      else if (s1 >= Kt) { j = 1; sAbove = s2; }
      else               { j = 0; sAbove = s1; }
      s_bin = 4 * tid + j; s_r = Kt - sAbove;
    }
    __syncthreads();
    unsigned int P1 = (unsigned int)s_bin;  // value bits [31:20]
    int r1 = s_r;
    __syncthreads();

    // ---- level 2: 256 bins on value bits [19:12] ----
    if (tid < 256) hs[tid] = 0;
    __syncthreads();
    for (int idx = tid; idx < M; idx += 1024) {
      unsigned long long kk = keysc[idx];
      if ((unsigned int)(kk >> 52) == P1)
        atomicAdd(&hs[(int)((kk >> 44) & 255ULL)], 1);
    }
    __syncthreads();
    for (int off = 1; off < 256; off <<= 1) {
      int v = 0;
      if (tid < 256 && tid + off < 256) v = hs[tid + off];
      __syncthreads();
      if (tid < 256) hs[tid] += v;
      __syncthreads();
    }
    if (tid < 256) {
      int above = (tid == 255) ? 0 : hs[tid + 1];
      if (hs[tid] >= r1 && above < r1) { s_bin = tid; s_r = r1 - above; }
    }
    __syncthreads();
    unsigned int P2 = (P1 << 8) | (unsigned int)s_bin;  // value bits [31:12]
    int r2 = s_r;
    __syncthreads();

    // ---- level 3: 256 bins on value bits [11:4] ----
    if (tid < 256) hs[tid] = 0;
    __syncthreads();
    for (int idx = tid; idx < M; idx += 1024) {
      unsigned long long kk = keysc[idx];
      if ((unsigned int)(kk >> 44) == P2)
        atomicAdd(&hs[(int)((kk >> 36) & 255ULL)], 1);
    }
    __syncthreads();
    for (int off = 1; off < 256; off <<= 1) {
      int v = 0;
      if (tid < 256 && tid + off < 256) v = hs[tid + off];
      __syncthreads();
      if (tid < 256) hs[tid] += v;
      __syncthreads();
    }
    if (tid < 256) {
      int above = (tid == 255) ? 0 : hs[tid + 1];
      if (hs[tid] >= r2 && above < r2) { s_bin = tid; s_r = r2 - above; }
    }
    __syncthreads();
    unsigned int P3 = (P2 << 8) | (unsigned int)s_bin;  // value bits [31:4]
    int r3 = s_r;
    __syncthreads();

    // ---- level 4: 16 bins on value bits [3:0] ----
    if (tid < 16) hs[tid] = 0;
    __syncthreads();
    for (int idx = tid; idx < M; idx += 1024) {
      unsigned long long kk = keysc[idx];
      if ((unsigned int)(kk >> 36) == P3)
        atomicAdd(&hs[(int)((kk >> 32) & 15ULL)], 1);
    }
    __syncthreads();
    for (int off = 1; off < 16; off <<= 1) {
      int v = 0;
      if (tid < 16 && tid + off < 16) v = hs[tid + off];
      __syncthreads();
      if (tid < 16) hs[tid] += v;
      __syncthreads();
    }
    if (tid < 16) {
      int above = (tid == 15) ? 0 : hs[tid + 1];
      if (hs[tid] >= r3 && above < r3) s_bin = tid;
    }
    __syncthreads();
    unsigned int V = (P3 << 4) | (unsigned int)s_bin;   // exact rank-K 32-bit value
    thresh64 = ((unsigned long long)V) << 32;           // value>=V <=> key>=thresh64
  }

  // ---- collect winners ----
  if (tid == 0) s_num = 0;
  __syncthreads();
  for (int idx = tid; idx < M; idx += 1024) {
    unsigned long long kk = keysc[idx];
    if (kk >= thresh64) {
      int w = atomicAdd(&s_num, 1);
      if (w < 1024) wins[w] = kk;
    }
  }
  __syncthreads();
  int n = s_num; if (n > 1024) n = 1024;
  // ---- exact rank by comparison (keys unique -> unique ranks) ----
  if (tid < n) {
    unsigned long long mine = wins[tid];
    int r = 0;
    for (int j = 0; j < n; ++j) r += (wins[j] > mine) ? 1 : 0;
    if (r < KC) {
      unsigned int key32 = (unsigned int)(mine >> 32);
      unsigned int idx = 0xFFFFFFFFu - (unsigned int)(mine & 0xFFFFFFFFULL);
      int bb = (int)(idx >> 18), rem = (int)(idx & (HWl - 1));
      cand_val[r] = __uint_as_float(key32);
      cand_bid[r] = bb; cand_cy[r] = rem >> 9; cand_cx[r] = rem & (W_ - 1);
    }
  }
  if (tid >= n && tid < KC) {  // unfilled slots (only when n < KC)
    cand_val[tid] = -1e30f; cand_bid[tid] = 0; cand_cy[tid] = 0; cand_cx[tid] = 0;
  }
}

// per-candidate window count of thing pixels (exact integer == f32 integral image).
// Block 0 also zeroes the global segment sums (written only by the later k_fused).
__global__ __launch_bounds__(256) void k_wsum(
    const int* __restrict__ sem, const float* __restrict__ mix,
    const float* __restrict__ cand_val, const int* __restrict__ cand_bid,
    const int* __restrict__ cand_cy, const int* __restrict__ cand_cx,
    int* __restrict__ selected, int* __restrict__ gz) {
  __shared__ int ssum[256];
  if (blockIdx.x == 0) {
    for (int q = threadIdx.x; q < 3 * (KC + 1) * B_; q += 256) gz[q] = 0;
  }
  int k = blockIdx.x;
  int b = cand_bid[k], cy = cand_cy[k], cx = cand_cx[k];
  float v = cand_val[k];
  int y0 = cy - 25; if (y0 < 0) y0 = 0;
  int y1 = cy + 26; if (y1 > H_) y1 = H_;
  int x0 = cx - 25; if (x0 < 0) x0 = 0;
  int x1 = cx + 26; if (x1 > W_) x1 = W_;
  int wd = x1 - x0, tot = (y1 - y0) * wd;
  int s = 0;
  for (int t = threadIdx.x; t < tot; t += 256) {
    int yy = y0 + t / wd, xx = x0 + t % wd;
    int sv = sem[b * HWl + yy * W_ + xx];
    s += (sv >= 11 && sv <= 18) ? 1 : 0;
  }
  ssum[threadIdx.x] = s;
  __syncthreads();
  for (int o = 128; o > 0; o >>= 1) {
    if (threadIdx.x < o) ssum[threadIdx.x] += ssum[threadIdx.x + o];
    __syncthreads();
  }
  if (threadIdx.x == 0) {
    bool sel = (v >= 0.1f) && (mix[b * HWl + cy * W_ + cx] < 0.5f) && (ssum[0] >= 64);
    selected[k] = sel ? 1 : 0;
  }
}

// fused (4 px/thread): inline center-list build (per-block ballot compaction),
// nearest-center argmin, Gaussian max-splat over a prefiltered local list,
// instance ids + local 201-bin LDS mass sums flushed to global per block
__global__ __launch_bounds__(256) void k_fused(
    const float* __restrict__ offs, const int* __restrict__ sem,
    const int* __restrict__ cand_bid, const int* __restrict__ cand_cy,
    const int* __restrict__ cand_cx, const int* __restrict__ selected,
    int* __restrict__ ins, float* __restrict__ out,
    int* __restrict__ gsy, int* __restrict__ gsx, int* __restrict__ gcn) {
  __shared__ float4 sc[KC];
  __shared__ float2 gl[KC];
  __shared__ int lsy[KC + 1], lsx[KC + 1], lcn[KC + 1];
  __shared__ int wtot[4];
  __shared__ int gcnt_s;
  int tid = threadIdx.x;
  int t = blockIdx.x * 256 + tid;   // t < 131072
  int p = t << 2;
  int b = p >> 18;                  // uniform per block
  int rem = p & (HWl - 1), y = rem >> 9, x0i = rem & (W_ - 1);
  int yA = (int)(((unsigned)(blockIdx.x * 1024) & (HWl - 1)) >> 9);  // block's first row

  for (int q = tid; q <= KC; q += 256) { lsy[q] = 0; lsx[q] = 0; lcn[q] = 0; }
  if (tid == 0) gcnt_s = 0;
  // ---- inline "final": build this batch's packed center list (rank order) ----
  bool sel = false; int cb = 0, ccy = 0, ccx = 0;
  if (tid < KC) { sel = selected[tid] != 0; cb = cand_bid[tid]; ccy = cand_cy[tid]; ccx = cand_cx[tid]; }
  bool mine = sel && (cb == b);
  unsigned long long mk = __ballot(mine);
  int lane = tid & 63, wv = tid >> 6;
  if (lane == 0) wtot[wv] = __popcll(mk);
  __syncthreads();
  int base = 0;
  for (int w2 = 0; w2 < wv; ++w2) base += wtot[w2];
  int S = wtot[0] + wtot[1] + wtot[2] + wtot[3];
  if (mine) {
    int pos = base + __popcll(mk & ((1ULL << lane) - 1ULL));
    float fyc = (float)ccy, fxc = (float)ccx;
    float cc = __fadd_rn(__fmul_rn(fyc, fyc), __fmul_rn(fxc, fxc));
    sc[pos] = make_float4(fyc, fxc, cc, 0.0f);
  }
  __syncthreads();
  // ---- prefilter Gaussian-relevant centers for this block's 2 rows ----
  if (tid < S) {
    float cyv = sc[tid].x;
    if (cyv >= (float)(yA - 25) && cyv <= (float)(yA + 26)) {
      int gp = atomicAdd(&gcnt_s, 1);
      gl[gp] = make_float2(cyv, sc[tid].y);
    }
  }
  __syncthreads();
  int G = gcnt_s;

  float fy = (float)y;
  float4 oy4 = *(const float4*)(offs + b * 2 * HWl + rem);
  float4 ox4 = *(const float4*)(offs + b * 2 * HWl + HWl + rem);
  float oyv[4] = {oy4.x, oy4.y, oy4.z, oy4.w};
  float oxv[4] = {ox4.x, ox4.y, ox4.z, ox4.w};
  float lyv[4], lxv[4], llv[4], bd[4];
  int bsg[4];
#pragma unroll
  for (int j = 0; j < 4; ++j) {
    float fx = (float)(x0i + j);
    // exact op order of reference: ll = ly*ly + lx*lx (no FMA)
    lyv[j] = __fadd_rn(fy, oyv[j]);
    lxv[j] = __fadd_rn(fx, oxv[j]);
    llv[j] = __fadd_rn(__fmul_rn(lyv[j], lyv[j]), __fmul_rn(lxv[j], lxv[j]));
    bd[j] = 3.0e38f; bsg[j] = 0;
  }
  // argmin over all S (exact expanded-quadratic op order; first-min tie-break)
  for (int s = 0; s < S; ++s) {
    float4 c = sc[s];
#pragma unroll
    for (int j = 0; j < 4; ++j) {
      float dot = __fadd_rn(__fmul_rn(c.x, lyv[j]), __fmul_rn(c.y, lxv[j]));
      float d2 = __fadd_rn(__fsub_rn(c.z, __fmul_rn(2.0f, dot)), llv[j]);
      bool better = d2 < bd[j];
      bd[j] = better ? d2 : bd[j];
      bsg[j] = better ? (s + 1) : bsg[j];
    }
  }
  // Gaussian max-splat over prefiltered list (fp max is order-independent)
  float bg[4] = {0.0f, 0.0f, 0.0f, 0.0f};
  for (int g = 0; g < G; ++g) {
    float2 gc = gl[g];
    float dyc = fy - gc.x;
    if (fabsf(dyc) <= 25.0f) {
      float gy = expf(-__fmul_rn(__fmul_rn(dyc, dyc), INV2S2));
#pragma unroll
      for (int j = 0; j < 4; ++j) {
        float dxc = (float)(x0i + j) - gc.y;
        if (fabsf(dxc) <= 25.0f) {
          float gx = expf(-__fmul_rn(__fmul_rn(dxc, dxc), INV2S2));
          bg[j] = fmaxf(bg[j], __fmul_rn(gy, gx));
        }
      }
    }
  }
  *(float4*)(out + OUT_CENTER + p) = make_float4(bg[0], bg[1], bg[2], bg[3]);
  int4 sv4 = *(const int4*)(sem + p);
  int svv[4] = {sv4.x, sv4.y, sv4.z, sv4.w};
  int insv[4];
  bool s_any = S > 0;
#pragma unroll
  for (int j = 0; j < 4; ++j) {
    bool thing = (svv[j] >= 11 && svv[j] <= 18);
    insv[j] = (thing && s_any) ? bsg[j] : 0;
  }
  *(int4*)(ins + p) = make_int4(insv[0], insv[1], insv[2], insv[3]);
  // merged per-thread local-bin accumulation (adjacent px often share a segment)
  int curSeg = -1, aY = 0, aX = 0, aC = 0;
#pragma unroll
  for (int j = 0; j < 4; ++j) {
    if (insv[j] > 0) {
      int sg = insv[j];
      if (sg != curSeg) {
        if (curSeg >= 0) {
          atomicAdd(&lsy[curSeg], aY); atomicAdd(&lsx[curSeg], aX); atomicAdd(&lcn[curSeg], aC);
        }
        curSeg = sg; aY = 0; aX = 0; aC = 0;
      }
      aY += y; aX += x0i + j; aC += 1;
    }
  }
  if (curSeg >= 0) {
    atomicAdd(&lsy[curSeg], aY); atomicAdd(&lsx[curSeg], aX); atomicAdd(&lcn[curSeg], aC);
  }
  __syncthreads();
  for (int q = tid; q <= KC; q += 256) {
    int c = lcn[q];
    if (c) {
      int gq = b * (KC + 1) + q;
      atomicAdd(&gcn[gq], c); atomicAdd(&gsy[gq], lsy[q]); atomicAdd(&gsx[gq], lsx[q]);
    }
  }
}

// offsets (4 px/thread) + center/offset weights
__global__ __launch_bounds__(256) void k_off(
    const int* __restrict__ ins, const int* __restrict__ gsy,
    const int* __restrict__ gsx, const int* __restrict__ gcn,
    float* __restrict__ out) {
  int t = blockIdx.x * 256 + threadIdx.x;   // t < 131072
  int p = t << 2;
  int b = p >> 18, rem = p & (HWl - 1), y = rem >> 9, x0i = rem & (W_ - 1);
  int4 iv = *(const int4*)(ins + p);
  int insv[4] = {iv.x, iv.y, iv.z, iv.w};
  float oy[4], ox[4], ow[4];
  float fy = (float)y;
#pragma unroll
  for (int j = 0; j < 4; ++j) {
    if (insv[j] > 0) {
      int sg = b * (KC + 1) + insv[j];
      float c = fmaxf((float)gcn[sg], 1.0f);
      oy[j] = __fsub_rn((float)gsy[sg] / c, fy);
      ox[j] = __fsub_rn((float)gsx[sg] / c, (float)(x0i + j));
      ow[j] = 1.0f;
    } else { oy[j] = 0.0f; ox[j] = 0.0f; ow[j] = 0.0f; }
  }
  *(float4*)(out + OUT_OFF + b * 2 * HWl + rem) = make_float4(oy[0], oy[1], oy[2], oy[3]);
  *(float4*)(out + OUT_OFF + b * 2 * HWl + HWl + rem) = make_float4(ox[0], ox[1], ox[2], ox[3]);
  *(float4*)(out + OUT_CW + p) = make_float4(1.0f, 1.0f, 1.0f, 1.0f);
  *(float4*)(out + OUT_OW + p) = make_float4(ow[0], ow[1], ow[2], ow[3]);
}

// ---------------- launch ----------------
extern "C" void kernel_launch(void* const* d_in, const int* in_sizes, int n_in,
                              void* d_out, int out_size, void* d_ws, size_t ws_size,
                              hipStream_t stream) {
  const float* ctr = (const float*)d_in[0];
  const float* offs = (const float*)d_in[1];
  const int* sem = (const int*)d_in[2];
  const float* mix = (const float*)d_in[3];
  float* out = (float*)d_out;

  char* w = (char*)d_ws;
  int* bcount = (int*)(w + 0);                          // NBLK ints, fully rewritten
  float* cand_val = (float*)(w + 1024);
  int* cand_bid = (int*)(w + 2048);
  int* cand_cy = (int*)(w + 3072);
  int* cand_cx = (int*)(w + 4096);
  int* selected = (int*)(w + 5120);
  int* gz = (int*)(w + 6144);                           // gsy|gsx|gcn, 3*402 ints
  int* gsy = gz;
  int* gsx = gz + (KC + 1) * B_;
  int* gcn = gz + 2 * (KC + 1) * B_;
  // keys: NBLK*1024*8 = 2 MB at 16384; ins (2 MB) OVERLAYS keys (keys dead
  // after k_topk; k_fused runs strictly later in-stream). keysc after keys.
  unsigned long long* keys = (unsigned long long*)(w + 16384);
  int* ins = (int*)(w + 16384);
  unsigned long long* keysc = (unsigned long long*)(w + 16384 + (size_t)NBLK * 1024 * 8);

  k_nms<<<NBLK, 256, 0, stream>>>(ctr, keys, bcount);
  k_topk<<<1, 1024, 0, stream>>>(keys, bcount, keysc,
                                 cand_val, cand_bid, cand_cy, cand_cx);
  k_wsum<<<KC, 256, 0, stream>>>(sem, mix, cand_val, cand_bid, cand_cy, cand_cx,
                                 selected, gz);
  k_fused<<<512, 256, 0, stream>>>(offs, sem, cand_bid, cand_cy, cand_cx, selected,
                                   ins, out, gsy, gsx, gcn);
  k_off<<<512, 256, 0, stream>>>(ins, gsy, gsx, gcn, out);
}